// Round 9
// baseline (304.077 us; speedup 1.0000x reference)
//
#include <hip/hip_runtime.h>
#include <hip/hip_bf16.h>

#define NN 100000
#define EE 1000000
#define H_DIM 124
#define PCOLS 512
#define LDK 136   // 128 + 8 bf16 pad
#define CW 132    // f32 staging stride in dwords

typedef float f32x4 __attribute__((ext_vector_type(4)));
typedef unsigned int u32x4 __attribute__((ext_vector_type(4)));
typedef short bf16x8 __attribute__((ext_vector_type(8)));
typedef _Float16 h2 __attribute__((ext_vector_type(2)));

__device__ __forceinline__ unsigned short f2bf(float f) {
    unsigned int x = __float_as_uint(f);
    unsigned int r = (x + 0x7FFFu + ((x >> 16) & 1u)) >> 16;
    return (unsigned short)r;
}
__device__ __forceinline__ unsigned int pk2bf(float a, float b) {
    return (unsigned int)f2bf(a) | ((unsigned int)f2bf(b) << 16);
}
__device__ __forceinline__ unsigned int pk2h(float a, float b) {
    h2 v = (h2){(_Float16)a, (_Float16)b};
    return __builtin_bit_cast(unsigned int, v);
}

__device__ __forceinline__ float fdot2(h2 a, h2 b, float c) {
#if __has_builtin(__builtin_amdgcn_fdot2)
    return __builtin_amdgcn_fdot2(a, b, c, false);
#else
    return c + (float)a[0] * (float)b[0] + (float)a[1] * (float)b[1];
#endif
}

#if __has_builtin(__builtin_amdgcn_update_dpp)
template <int CTRL>
__device__ __forceinline__ float dpp_add(float x) {
    int xi = __builtin_bit_cast(int, x);
    int t = __builtin_amdgcn_update_dpp(xi, xi, CTRL, 0xF, 0xF, false);
    return x + __builtin_bit_cast(float, t);
}
__device__ __forceinline__ float reduce16(float x) {
    x = dpp_add<0x128>(x);   // row_ror:8
    x = dpp_add<0x124>(x);   // row_ror:4
    x = dpp_add<0x122>(x);   // row_ror:2
    x = dpp_add<0x121>(x);   // row_ror:1
    return x;
}
#else
__device__ __forceinline__ float reduce16(float x) {
    x += __shfl_xor(x, 8); x += __shfl_xor(x, 4);
    x += __shfl_xor(x, 2); x += __shfl_xor(x, 1);
    return x;
}
#endif

// ---------------- Kernel 1: W1T (bf16 [512,128]) + packed constant table ----------------
__global__ __launch_bounds__(256) void build_w1t_ct(const float* __restrict__ W1,
                                                    const float* __restrict__ gamma,
                                                    const float* __restrict__ beta,
                                                    const float* __restrict__ W2,
                                                    unsigned short* __restrict__ W1T,
                                                    uint4* __restrict__ CT) {
    if (blockIdx.x < 256) {
        int t2 = blockIdx.x * 256 + threadIdx.x;     // 0 .. 65535
        int j = t2 >> 7, k = t2 & 127;
        int row = (j < 256) ? k : (130 + k);
        int col = (j < 256) ? j : (j - 256);
        W1T[t2] = f2bf(W1[row * 256 + col]);
    } else {
        int t = threadIdx.x;
        if (t < 192) {
            int slot = t % 12, il = t / 12;
            int a = slot >> 1, k = slot & 1;
            int j0 = il * 16 + k * 8;
            float v[8];
            #pragma unroll
            for (int i = 0; i < 8; ++i) {
                int j = j0 + i;
                v[i] = (a == 0) ? W1[128 * 256 + j]
                     : (a == 1) ? W1[129 * 256 + j]
                     : (a == 2) ? gamma[j]
                     : (a == 3) ? beta[j]
                     : (a == 4) ? W2[2 * j]
                     :            W2[2 * j + 1];
            }
            CT[t] = make_uint4(pk2h(v[0], v[1]), pk2h(v[2], v[3]),
                               pk2h(v[4], v[5]), pk2h(v[6], v[7]));
        }
    }
}

// ---------------- Kernel 2: fused F-build + P = F @ W1cat (+b1 on dst half) -> fp16 ----------------
__global__ __launch_bounds__(256) void p_gemm(const float* __restrict__ h,
                                              const float* __restrict__ cls,
                                              const unsigned short* __restrict__ W1T,
                                              const float* __restrict__ b1,
                                              _Float16* __restrict__ P) {
    __shared__ alignas(16) unsigned short As[64 * LDK];
    __shared__ alignas(16) unsigned short Bs[128 * LDK];
    float* Cs = (float*)&Bs[0];
    const int m0 = blockIdx.x * 64;
    const int t = threadIdx.x;

    #pragma unroll
    for (int it = 0; it < 4; ++it) {
        int chunk = t + it * 256;
        int r = chunk >> 4, c8 = chunk & 15;
        int row = m0 + r;
        unsigned int w0 = 0, w1 = 0, w2 = 0, w3 = 0;
        if (row < NN) {
            if (c8 < 15) {
                const float* hp = h + (size_t)row * H_DIM + c8 * 8;
                float4 v0 = *(const float4*)(hp);
                float4 v1 = *(const float4*)(hp + 4);
                w0 = pk2bf(v0.x, v0.y); w1 = pk2bf(v0.z, v0.w);
                w2 = pk2bf(v1.x, v1.y); w3 = pk2bf(v1.z, v1.w);
            } else {
                float4 v0 = *(const float4*)(h + (size_t)row * H_DIM + 120);
                float4 c = *(const float4*)(cls + (size_t)row * 4);
                float m = fmaxf(fmaxf(c.x, c.y), fmaxf(c.z, c.w));
                float e0 = __expf(c.x - m), e1 = __expf(c.y - m);
                float e2 = __expf(c.z - m), e3 = __expf(c.w - m);
                float inv = 1.0f / (e0 + e1 + e2 + e3);
                w0 = pk2bf(v0.x, v0.y); w1 = pk2bf(v0.z, v0.w);
                w2 = pk2bf(e0 * inv, e1 * inv); w3 = pk2bf(e2 * inv, e3 * inv);
            }
        }
        *(uint4*)(&As[r * LDK + c8 * 8]) = make_uint4(w0, w1, w2, w3);
    }
    __syncthreads();

    const int wave = t >> 6, lane = t & 63;
    const int wm = wave & 1, wn = wave >> 1;
    const int lm = lane & 15, quad = lane >> 4;

    bf16x8 afrag[4][2];
    #pragma unroll
    for (int s = 0; s < 4; ++s) {
        int k0 = s * 32 + quad * 8;
        #pragma unroll
        for (int mt = 0; mt < 2; ++mt)
            afrag[s][mt] = *(const bf16x8*)(&As[(wm * 32 + mt * 16 + lm) * LDK + k0]);
    }

    for (int cchunk = 0; cchunk < 4; ++cchunk) {
        const int n0 = cchunk * 128;
        if (cchunk) __syncthreads();
        #pragma unroll
        for (int it = 0; it < 8; ++it) {
            int chunk = t + it * 256;
            int r = chunk >> 4, c = chunk & 15;
            float4 v = *(const float4*)(W1T + (n0 + r) * 128 + c * 8);
            *(float4*)(&Bs[r * LDK + c * 8]) = v;
        }
        __syncthreads();

        f32x4 acc[2][4];
        #pragma unroll
        for (int mt = 0; mt < 2; ++mt)
            #pragma unroll
            for (int nt = 0; nt < 4; ++nt)
                acc[mt][nt] = (f32x4){0.f, 0.f, 0.f, 0.f};

        #pragma unroll
        for (int s = 0; s < 4; ++s) {
            int k0 = s * 32 + quad * 8;
            bf16x8 b[4];
            #pragma unroll
            for (int nt = 0; nt < 4; ++nt)
                b[nt] = *(const bf16x8*)(&Bs[(wn * 64 + nt * 16 + lm) * LDK + k0]);
            #pragma unroll
            for (int mt = 0; mt < 2; ++mt)
                #pragma unroll
                for (int nt = 0; nt < 4; ++nt)
                    acc[mt][nt] = __builtin_amdgcn_mfma_f32_16x16x32_bf16(afrag[s][mt], b[nt], acc[mt][nt], 0, 0, 0);
        }
        __syncthreads();

        #pragma unroll
        for (int mt = 0; mt < 2; ++mt)
            #pragma unroll
            for (int nt = 0; nt < 4; ++nt) {
                int col = wn * 64 + nt * 16 + lm;
                int rb  = wm * 32 + mt * 16 + quad * 4;
                #pragma unroll
                for (int r = 0; r < 4; ++r)
                    Cs[(rb + r) * CW + col] = acc[mt][nt][r];
            }
        __syncthreads();

        #pragma unroll
        for (int it = 0; it < 4; ++it) {
            int chunk = t + it * 256;
            int r = chunk >> 4, c8 = chunk & 15;
            float4 a = *(const float4*)(Cs + r * CW + c8 * 8);
            float4 b = *(const float4*)(Cs + r * CW + c8 * 8 + 4);
            if (n0 >= 256) {   // dst half: fold b1 (wave-uniform branch)
                int cb = n0 + c8 * 8 - 256;
                float4 ba = *(const float4*)(b1 + cb);
                float4 bb = *(const float4*)(b1 + cb + 4);
                a.x += ba.x; a.y += ba.y; a.z += ba.z; a.w += ba.w;
                b.x += bb.x; b.y += bb.y; b.z += bb.z; b.w += bb.w;
            }
            uint4 o = make_uint4(pk2h(a.x, a.y), pk2h(a.z, a.w),
                                 pk2h(b.x, b.y), pk2h(b.z, b.w));
            int row = m0 + r;
            if (row < NN)
                *(uint4*)(P + (size_t)row * PCOLS + n0 + c8 * 8) = o;
        }
    }
}

// ---------------- Kernel 3: edges — depth-2 LDS pipeline, counted vmcnt ----------------
// R7 was depth-1 (vmcnt(0)/round: stall = L - 1 round). Now depth-2: P[r+2]
// issued at round r; waits are counted. Safe because the steady-state loop
// contains ONLY my vmem ops (4 P-DMA + 1 idx-DMA + 1 store per round;
// constants preloaded, no spill at ~60 VGPR). FIFO simulated across all 16
// rounds incl. prologue/tail and store-placement freedom: retired set each
// round = {P[r]x4, idx[r+2], store[r-2]} for ANY store position (oldest-6
// membership is position-invariant). Waits: r0=5, r1..14=6, r15=2. Worst
// failure = stale LDS -> wrong answer (indices clamped -> no fault).
// P: 3 buffers x 4KB; idx: 5 buffers x 256B (slot r%5 written only at
// round r-4's issue of idx[r], q[r] read at round r, overwrite idx[r+5]
// issued at round r+1 -> no overlap).
#define K3_BLOCKS 4096
#define K3_STRIDE 65536
#define K3_ROUNDS 16                   // 16*65536 >= EE
#define PWB 13568                      // per-wave LDS: 3*4096 + 5*256

__device__ __forceinline__ void stage16(const void* g, void* l) {
#if __has_builtin(__builtin_amdgcn_global_load_lds)
    __builtin_amdgcn_global_load_lds((const __attribute__((address_space(1))) void*)g,
                                     (__attribute__((address_space(3))) void*)l, 16, 0, 0);
#else
    int ln = threadIdx.x & 63;
    *(uint4*)((char*)l + ln * 16) = *(const uint4*)g;
#endif
}
__device__ __forceinline__ void stage4(const void* g, void* l) {
#if __has_builtin(__builtin_amdgcn_global_load_lds)
    __builtin_amdgcn_global_load_lds((const __attribute__((address_space(1))) void*)g,
                                     (__attribute__((address_space(3))) void*)l, 4, 0, 0);
#else
    int ln = threadIdx.x & 63;
    *(unsigned*)((char*)l + ln * 4) = *(const unsigned*)g;
#endif
}

__device__ __forceinline__ h2 pick(const u32x4& x0, const u32x4& x1, int j) {
    unsigned v = (j < 4) ? x0[j] : x1[j - 4];
    return __builtin_bit_cast(h2, v);
}

__global__ __launch_bounds__(256, 3) void edge_kernel(const _Float16* __restrict__ P,
                                                      const int* __restrict__ src,
                                                      const int* __restrict__ dst,
                                                      const float* __restrict__ polar,
                                                      const uint4* __restrict__ CT,
                                                      const float* __restrict__ b2,
                                                      float* __restrict__ out) {
    __shared__ alignas(16) char SB[4 * PWB];   // 54,272 B -> 3 blocks/CU
    const int t    = threadIdx.x;
    const int lane = t & 63;
    const int w    = t >> 6;
    const int il   = lane & 15;
    const int g    = lane >> 4;
    const int wid  = blockIdx.x * 4 + w;
    const int ebase = wid * 4;          // edge of group g, round r: ebase + g + r*K3_STRIDE

    char* pb = SB + w * PWB;            // 3 x 4096 P buffers
    char* ib = pb + 12288;              // 5 x 256 idx buffers

    // constants (plain loads; prologue vmcnt(0) below drains them too)
    uint4 cq[12];
    #pragma unroll
    for (int i = 0; i < 12; ++i) cq[i] = CT[il * 12 + i];
    h2 w0c[8], w1c[8], gc[8], bc[8], w2ac[8], w2bc[8];
    {
        const h2* ch = (const h2*)cq;
        #pragma unroll
        for (int p = 0; p < 8; ++p) {
            w0c[p]  = ch[p];      w1c[p]  = ch[8 + p];
            gc[p]   = ch[16 + p]; bc[p]   = ch[24 + p];
            w2ac[p] = ch[32 + p]; w2bc[p] = ch[40 + p];
        }
    }
    const float b20 = b2[0], b21 = b2[1];
    const h2 onep  = (h2){(_Float16)1.0f, (_Float16)1.0f};
    const h2 zerop = (h2){(_Float16)0.0f, (_Float16)0.0f};

    // idx staging lane roles (lanes >=16 mirror il; duplicate addrs coalesce)
    // ibuf dwords: [0..3]=s(e0..e3)  [4..7]=d(e0..e3)  [8..15]=q0,q1 pairs per edge
    const int sel  = (il < 4) ? 0 : (il < 8) ? 1 : 2;
    const int eoff = (il < 4) ? il : (il < 8) ? (il - 4) : ((il - 8) >> 1);
    const int comp = (sel == 2) ? (il & 1) : 0;

    #define IDX_GADDR(rr)                                                      \
        ((sel == 0) ? (const void*)(src + (((ebase + eoff + (rr) * K3_STRIDE) < EE) ? (ebase + eoff + (rr) * K3_STRIDE) : (EE - 1))) \
       : (sel == 1) ? (const void*)(dst + (((ebase + eoff + (rr) * K3_STRIDE) < EE) ? (ebase + eoff + (rr) * K3_STRIDE) : (EE - 1))) \
       :              (const void*)(polar + 2 * (size_t)(((ebase + eoff + (rr) * K3_STRIDE) < EE) ? (ebase + eoff + (rr) * K3_STRIDE) : (EE - 1)) + comp))

    #define ISSUE_P(j) {                                                       \
        const unsigned* inx = (const unsigned*)(ib + ((j) % 5) * 256);         \
        unsigned sv = inx[g], dv = inx[4 + g];                                 \
        sv = (sv < NN) ? sv : 0u; dv = (dv < NN) ? dv : 0u;                    \
        char* pn = pb + ((j) % 3) * 4096;                                      \
        const char* srow = (const char*)P + ((size_t)sv << 10) + il * 32;      \
        const char* drow = (const char*)P + ((size_t)dv << 10) + 512 + il * 32;\
        stage16(srow, pn);          stage16(srow + 16, pn + 1024);             \
        stage16(drow, pn + 2048);   stage16(drow + 16, pn + 3072); }

    // ---- prologue: FIFO after = [P0(4), idx2, P1(4), idx3] = 10 ----
    stage4(IDX_GADDR(0), ib + 0 * 256);
    stage4(IDX_GADDR(1), ib + 1 * 256);
    asm volatile("s_waitcnt vmcnt(0)" ::: "memory");
    __builtin_amdgcn_sched_barrier(0);
    ISSUE_P(0);
    stage4(IDX_GADDR(2), ib + 2 * 256);
    ISSUE_P(1);
    stage4(IDX_GADDR(3), ib + 3 * 256);

    // ---- main loop (fully unrolled; r compile-time) ----
    #pragma unroll
    for (int r = 0; r < K3_ROUNDS; ++r) {
        if (r == 0)       { asm volatile("s_waitcnt vmcnt(5)" ::: "memory"); }
        else if (r == 15) { asm volatile("s_waitcnt vmcnt(2)" ::: "memory"); }
        else              { asm volatile("s_waitcnt vmcnt(6)" ::: "memory"); }
        __builtin_amdgcn_sched_barrier(0);

        if (r + 2 < K3_ROUNDS) ISSUE_P(r + 2);                       // rounds 0..13
        if (r + 4 < K3_ROUNDS) stage4(IDX_GADDR(r + 4), ib + ((r + 4) % 5) * 256); // 0..11

        // ---- compute round r: P from pb slot r%3, q from ib slot r%5 ----
        const char* pcur = pb + (r % 3) * 4096;
        const char* icur = ib + (r % 5) * 256;
        float2 qv = *(const float2*)(icur + 32 + 8 * g);
        u32x4 a0 = *(const u32x4*)(pcur + lane * 16);
        u32x4 a1 = *(const u32x4*)(pcur + 1024 + lane * 16);
        u32x4 c0 = *(const u32x4*)(pcur + 2048 + lane * 16);
        u32x4 c1 = *(const u32x4*)(pcur + 3072 + lane * 16);

        h2 p0 = (h2){(_Float16)qv.x, (_Float16)qv.x};
        h2 p1 = (h2){(_Float16)qv.y, (_Float16)qv.y};
        h2 z[8];
        float sum = 0.f, ss = 0.f;
        #pragma unroll
        for (int p = 0; p < 8; ++p) {
            h2 pv = pick(a0, a1, p) + pick(c0, c1, p);
            h2 cc = w0c[p] * p0 + w1c[p] * p1;
            z[p] = pv + cc;
            sum = fdot2(z[p], onep, sum);
            ss  = fdot2(z[p], z[p], ss);
        }
        sum = reduce16(sum); ss = reduce16(ss);
        float mu   = sum * (1.0f / 256.0f);
        float var  = ss * (1.0f / 256.0f) - mu * mu;
        float rstd = rsqrtf(var + 1e-5f);
        float nmur = -mu * rstd;
        h2 rsh = (h2){(_Float16)rstd, (_Float16)rstd};
        h2 nmh = (h2){(_Float16)nmur, (_Float16)nmur};
        float o0 = 0.f, o1 = 0.f;
        #pragma unroll
        for (int p = 0; p < 8; ++p) {
            h2 tt = z[p] * rsh + nmh;
            h2 u  = tt * gc[p] + bc[p];
            u = __builtin_elementwise_max(u, zerop);
            o0 = fdot2(u, w2ac[p], o0);
            o1 = fdot2(u, w2bc[p], o1);
        }
        o0 = reduce16(o0); o1 = reduce16(o1);
        int eg = ebase + g + r * K3_STRIDE;
        if (il == 0 && eg < EE)     // can only skip at r=15 (after last counted wait)
            *(float2*)(out + 2 * (size_t)eg) = make_float2(o0 + b20, o1 + b21);
    }
    #undef ISSUE_P
    #undef IDX_GADDR
    asm volatile("s_waitcnt vmcnt(0)" ::: "memory");   // drain stores
}

extern "C" void kernel_launch(void* const* d_in, const int* in_sizes, int n_in,
                              void* d_out, int out_size, void* d_ws, size_t ws_size,
                              hipStream_t stream) {
    const float* h     = (const float*)d_in[0];
    const float* cls   = (const float*)d_in[1];
    const float* polar = (const float*)d_in[2];
    const int*   src   = (const int*)d_in[3];
    const int*   dst   = (const int*)d_in[4];
    const float* W1    = (const float*)d_in[5];
    const float* b1    = (const float*)d_in[6];
    const float* gamma = (const float*)d_in[7];
    const float* beta  = (const float*)d_in[8];
    const float* W2    = (const float*)d_in[9];
    const float* b2    = (const float*)d_in[10];
    float* out = (float*)d_out;

    char* ws = (char*)d_ws;
    _Float16*       P   = (_Float16*)ws;                      // N*512*2 = 102,400,000 B
    unsigned short* W1T = (unsigned short*)(ws + 102400000);  // 131,072 B
    uint4*          CT  = (uint4*)(ws + 102531072);           // 3,072 B

    build_w1t_ct<<<257, 256, 0, stream>>>(W1, gamma, beta, W2, W1T, CT);
    p_gemm<<<1563, 256, 0, stream>>>(h, cls, W1T, b1, P);
    edge_kernel<<<K3_BLOCKS, 256, 0, stream>>>(P, src, dst, polar, CT, b2, out);
}

// Round 10
// 287.911 us; speedup vs baseline: 1.0561x; 1.0561x over previous
//
#include <hip/hip_runtime.h>
#include <hip/hip_bf16.h>

#define NN 100000
#define EE 1000000
#define H_DIM 124
#define PCOLS 512
#define LDK 136   // 128 + 8 bf16 pad
#define CW 132    // f32 staging stride in dwords

typedef float f32x4 __attribute__((ext_vector_type(4)));
typedef unsigned int u32x4 __attribute__((ext_vector_type(4)));
typedef short bf16x8 __attribute__((ext_vector_type(8)));
typedef _Float16 h2 __attribute__((ext_vector_type(2)));

__device__ __forceinline__ unsigned short f2bf(float f) {
    unsigned int x = __float_as_uint(f);
    unsigned int r = (x + 0x7FFFu + ((x >> 16) & 1u)) >> 16;
    return (unsigned short)r;
}
__device__ __forceinline__ unsigned int pk2bf(float a, float b) {
    return (unsigned int)f2bf(a) | ((unsigned int)f2bf(b) << 16);
}
__device__ __forceinline__ unsigned int pk2h(float a, float b) {
    h2 v = (h2){(_Float16)a, (_Float16)b};
    return __builtin_bit_cast(unsigned int, v);
}

__device__ __forceinline__ float fdot2(h2 a, h2 b, float c) {
#if __has_builtin(__builtin_amdgcn_fdot2)
    return __builtin_amdgcn_fdot2(a, b, c, false);
#else
    return c + (float)a[0] * (float)b[0] + (float)a[1] * (float)b[1];
#endif
}

#if __has_builtin(__builtin_amdgcn_update_dpp)
template <int CTRL>
__device__ __forceinline__ float dpp_add(float x) {
    int xi = __builtin_bit_cast(int, x);
    int t = __builtin_amdgcn_update_dpp(xi, xi, CTRL, 0xF, 0xF, false);
    return x + __builtin_bit_cast(float, t);
}
__device__ __forceinline__ float reduce16(float x) {
    x = dpp_add<0x128>(x);   // row_ror:8
    x = dpp_add<0x124>(x);   // row_ror:4
    x = dpp_add<0x122>(x);   // row_ror:2
    x = dpp_add<0x121>(x);   // row_ror:1
    return x;
}
#else
__device__ __forceinline__ float reduce16(float x) {
    x += __shfl_xor(x, 8); x += __shfl_xor(x, 4);
    x += __shfl_xor(x, 2); x += __shfl_xor(x, 1);
    return x;
}
#endif

// ---------------- Kernel 1: W1T (bf16 [512,128]) + packed constant table ----------------
__global__ __launch_bounds__(256) void build_w1t_ct(const float* __restrict__ W1,
                                                    const float* __restrict__ gamma,
                                                    const float* __restrict__ beta,
                                                    const float* __restrict__ W2,
                                                    unsigned short* __restrict__ W1T,
                                                    uint4* __restrict__ CT) {
    if (blockIdx.x < 256) {
        int t2 = blockIdx.x * 256 + threadIdx.x;     // 0 .. 65535
        int j = t2 >> 7, k = t2 & 127;
        int row = (j < 256) ? k : (130 + k);
        int col = (j < 256) ? j : (j - 256);
        W1T[t2] = f2bf(W1[row * 256 + col]);
    } else {
        int t = threadIdx.x;
        if (t < 192) {
            int slot = t % 12, il = t / 12;
            int a = slot >> 1, k = slot & 1;
            int j0 = il * 16 + k * 8;
            float v[8];
            #pragma unroll
            for (int i = 0; i < 8; ++i) {
                int j = j0 + i;
                v[i] = (a == 0) ? W1[128 * 256 + j]
                     : (a == 1) ? W1[129 * 256 + j]
                     : (a == 2) ? gamma[j]
                     : (a == 3) ? beta[j]
                     : (a == 4) ? W2[2 * j]
                     :            W2[2 * j + 1];
            }
            CT[t] = make_uint4(pk2h(v[0], v[1]), pk2h(v[2], v[3]),
                               pk2h(v[4], v[5]), pk2h(v[6], v[7]));
        }
    }
}

// ---------------- Kernel 2: fused F-build + P = F @ W1cat (+b1 on dst half) -> fp16 ----------------
__global__ __launch_bounds__(256) void p_gemm(const float* __restrict__ h,
                                              const float* __restrict__ cls,
                                              const unsigned short* __restrict__ W1T,
                                              const float* __restrict__ b1,
                                              _Float16* __restrict__ P) {
    __shared__ alignas(16) unsigned short As[64 * LDK];
    __shared__ alignas(16) unsigned short Bs[128 * LDK];
    float* Cs = (float*)&Bs[0];
    const int m0 = blockIdx.x * 64;
    const int t = threadIdx.x;

    #pragma unroll
    for (int it = 0; it < 4; ++it) {
        int chunk = t + it * 256;
        int r = chunk >> 4, c8 = chunk & 15;
        int row = m0 + r;
        unsigned int w0 = 0, w1 = 0, w2 = 0, w3 = 0;
        if (row < NN) {
            if (c8 < 15) {
                const float* hp = h + (size_t)row * H_DIM + c8 * 8;
                float4 v0 = *(const float4*)(hp);
                float4 v1 = *(const float4*)(hp + 4);
                w0 = pk2bf(v0.x, v0.y); w1 = pk2bf(v0.z, v0.w);
                w2 = pk2bf(v1.x, v1.y); w3 = pk2bf(v1.z, v1.w);
            } else {
                float4 v0 = *(const float4*)(h + (size_t)row * H_DIM + 120);
                float4 c = *(const float4*)(cls + (size_t)row * 4);
                float m = fmaxf(fmaxf(c.x, c.y), fmaxf(c.z, c.w));
                float e0 = __expf(c.x - m), e1 = __expf(c.y - m);
                float e2 = __expf(c.z - m), e3 = __expf(c.w - m);
                float inv = 1.0f / (e0 + e1 + e2 + e3);
                w0 = pk2bf(v0.x, v0.y); w1 = pk2bf(v0.z, v0.w);
                w2 = pk2bf(e0 * inv, e1 * inv); w3 = pk2bf(e2 * inv, e3 * inv);
            }
        }
        *(uint4*)(&As[r * LDK + c8 * 8]) = make_uint4(w0, w1, w2, w3);
    }
    __syncthreads();

    const int wave = t >> 6, lane = t & 63;
    const int wm = wave & 1, wn = wave >> 1;
    const int lm = lane & 15, quad = lane >> 4;

    bf16x8 afrag[4][2];
    #pragma unroll
    for (int s = 0; s < 4; ++s) {
        int k0 = s * 32 + quad * 8;
        #pragma unroll
        for (int mt = 0; mt < 2; ++mt)
            afrag[s][mt] = *(const bf16x8*)(&As[(wm * 32 + mt * 16 + lm) * LDK + k0]);
    }

    for (int cchunk = 0; cchunk < 4; ++cchunk) {
        const int n0 = cchunk * 128;
        if (cchunk) __syncthreads();
        #pragma unroll
        for (int it = 0; it < 8; ++it) {
            int chunk = t + it * 256;
            int r = chunk >> 4, c = chunk & 15;
            float4 v = *(const float4*)(W1T + (n0 + r) * 128 + c * 8);
            *(float4*)(&Bs[r * LDK + c * 8]) = v;
        }
        __syncthreads();

        f32x4 acc[2][4];
        #pragma unroll
        for (int mt = 0; mt < 2; ++mt)
            #pragma unroll
            for (int nt = 0; nt < 4; ++nt)
                acc[mt][nt] = (f32x4){0.f, 0.f, 0.f, 0.f};

        #pragma unroll
        for (int s = 0; s < 4; ++s) {
            int k0 = s * 32 + quad * 8;
            bf16x8 b[4];
            #pragma unroll
            for (int nt = 0; nt < 4; ++nt)
                b[nt] = *(const bf16x8*)(&Bs[(wn * 64 + nt * 16 + lm) * LDK + k0]);
            #pragma unroll
            for (int mt = 0; mt < 2; ++mt)
                #pragma unroll
                for (int nt = 0; nt < 4; ++nt)
                    acc[mt][nt] = __builtin_amdgcn_mfma_f32_16x16x32_bf16(afrag[s][mt], b[nt], acc[mt][nt], 0, 0, 0);
        }
        __syncthreads();

        #pragma unroll
        for (int mt = 0; mt < 2; ++mt)
            #pragma unroll
            for (int nt = 0; nt < 4; ++nt) {
                int col = wn * 64 + nt * 16 + lm;
                int rb  = wm * 32 + mt * 16 + quad * 4;
                #pragma unroll
                for (int r = 0; r < 4; ++r)
                    Cs[(rb + r) * CW + col] = acc[mt][nt][r];
            }
        __syncthreads();

        #pragma unroll
        for (int it = 0; it < 4; ++it) {
            int chunk = t + it * 256;
            int r = chunk >> 4, c8 = chunk & 15;
            float4 a = *(const float4*)(Cs + r * CW + c8 * 8);
            float4 b = *(const float4*)(Cs + r * CW + c8 * 8 + 4);
            if (n0 >= 256) {   // dst half: fold b1 (wave-uniform branch)
                int cb = n0 + c8 * 8 - 256;
                float4 ba = *(const float4*)(b1 + cb);
                float4 bb = *(const float4*)(b1 + cb + 4);
                a.x += ba.x; a.y += ba.y; a.z += ba.z; a.w += ba.w;
                b.x += bb.x; b.y += bb.y; b.z += bb.z; b.w += bb.w;
            }
            uint4 o = make_uint4(pk2h(a.x, a.y), pk2h(a.z, a.w),
                                 pk2h(b.x, b.y), pk2h(b.z, b.w));
            int row = m0 + r;
            if (row < NN)
                *(uint4*)(P + (size_t)row * PCOLS + n0 + c8 * 8) = o;
        }
    }
}

// ---------------- Kernel 3: edges — depth-2 LDS pipeline, 2 P-buffers, 4 blocks/CU ----------------
// R8 lesson: depth-2 works (counted vmcnt with only-my-vmem is correct) but
// 3 P-buffers (54KB LDS) -> 2 blocks/CU killed occupancy. Fix: 2 P-buffers
// via read-then-overwrite ordering -- compute r's LDS reads complete before
// ISSUE_P(r+2) re-targets pb[r&1] in the same round (sched_barrier-pinned).
// Per-wave LDS = 2*4096 + 5*256 = 9472 -> block 37,888 -> 4 blocks/CU (16
// waves, R8's TLP) WITH ~2-round load slack (depth-2 ILP).
// FIFO (round order: [reads | P-issue(4), idx-issue(1) | compute+store(1)]):
// waits r0=5, r1=6, r2..12=7, r13=6, r14=6, r15=2; stores counted, only
// >=3-round-old ones ever waited. Stale worst-case = wrong answer (indices
// clamped -> no fault possible).
#define K3_BLOCKS 4096
#define K3_STRIDE 65536
#define K3_ROUNDS 16                   // 16*65536 >= EE
#define PWB 9472                       // per-wave LDS: 2*4096 + 5*256

__device__ __forceinline__ void stage16(const void* g, void* l) {
#if __has_builtin(__builtin_amdgcn_global_load_lds)
    __builtin_amdgcn_global_load_lds((const __attribute__((address_space(1))) void*)g,
                                     (__attribute__((address_space(3))) void*)l, 16, 0, 0);
#else
    int ln = threadIdx.x & 63;
    *(uint4*)((char*)l + ln * 16) = *(const uint4*)g;
#endif
}
__device__ __forceinline__ void stage4(const void* g, void* l) {
#if __has_builtin(__builtin_amdgcn_global_load_lds)
    __builtin_amdgcn_global_load_lds((const __attribute__((address_space(1))) void*)g,
                                     (__attribute__((address_space(3))) void*)l, 4, 0, 0);
#else
    int ln = threadIdx.x & 63;
    *(unsigned*)((char*)l + ln * 4) = *(const unsigned*)g;
#endif
}

__device__ __forceinline__ h2 pick(const u32x4& x0, const u32x4& x1, int j) {
    unsigned v = (j < 4) ? x0[j] : x1[j - 4];
    return __builtin_bit_cast(h2, v);
}

__global__ __launch_bounds__(256, 4) void edge_kernel(const _Float16* __restrict__ P,
                                                      const int* __restrict__ src,
                                                      const int* __restrict__ dst,
                                                      const float* __restrict__ polar,
                                                      const uint4* __restrict__ CT,
                                                      const float* __restrict__ b2,
                                                      float* __restrict__ out) {
    __shared__ alignas(16) char SB[4 * PWB];   // 37,888 B -> 4 blocks/CU
    const int t    = threadIdx.x;
    const int lane = t & 63;
    const int w    = t >> 6;
    const int il   = lane & 15;
    const int g    = lane >> 4;
    const int wid  = blockIdx.x * 4 + w;
    const int ebase = wid * 4;          // edge of group g, round r: ebase + g + r*K3_STRIDE

    char* pb = SB + w * PWB;            // 2 x 4096 P buffers
    char* ib = pb + 8192;               // 5 x 256 idx buffers

    // constants (plain loads; prologue vmcnt(0) below drains them too)
    uint4 cq[12];
    #pragma unroll
    for (int i = 0; i < 12; ++i) cq[i] = CT[il * 12 + i];
    h2 w0c[8], w1c[8], gc[8], bc[8], w2ac[8], w2bc[8];
    {
        const h2* ch = (const h2*)cq;
        #pragma unroll
        for (int p = 0; p < 8; ++p) {
            w0c[p]  = ch[p];      w1c[p]  = ch[8 + p];
            gc[p]   = ch[16 + p]; bc[p]   = ch[24 + p];
            w2ac[p] = ch[32 + p]; w2bc[p] = ch[40 + p];
        }
    }
    const float b20 = b2[0], b21 = b2[1];
    const h2 onep  = (h2){(_Float16)1.0f, (_Float16)1.0f};
    const h2 zerop = (h2){(_Float16)0.0f, (_Float16)0.0f};

    // idx staging lane roles (lanes >=16 mirror il; duplicate addrs coalesce)
    // ibuf dwords: [0..3]=s(e0..e3)  [4..7]=d(e0..e3)  [8..15]=q0,q1 pairs per edge
    const int sel  = (il < 4) ? 0 : (il < 8) ? 1 : 2;
    const int eoff = (il < 4) ? il : (il < 8) ? (il - 4) : ((il - 8) >> 1);
    const int comp = (sel == 2) ? (il & 1) : 0;

    #define IDX_GADDR(rr)                                                      \
        ((sel == 0) ? (const void*)(src + (((ebase + eoff + (rr) * K3_STRIDE) < EE) ? (ebase + eoff + (rr) * K3_STRIDE) : (EE - 1))) \
       : (sel == 1) ? (const void*)(dst + (((ebase + eoff + (rr) * K3_STRIDE) < EE) ? (ebase + eoff + (rr) * K3_STRIDE) : (EE - 1))) \
       :              (const void*)(polar + 2 * (size_t)(((ebase + eoff + (rr) * K3_STRIDE) < EE) ? (ebase + eoff + (rr) * K3_STRIDE) : (EE - 1)) + comp))

    #define ISSUE_P(j) {                                                       \
        const unsigned* inx = (const unsigned*)(ib + ((j) % 5) * 256);         \
        unsigned sv = inx[g], dv = inx[4 + g];                                 \
        sv = (sv < NN) ? sv : 0u; dv = (dv < NN) ? dv : 0u;                    \
        char* pn = pb + ((j) & 1) * 4096;                                      \
        const char* srow = (const char*)P + ((size_t)sv << 10) + il * 32;      \
        const char* drow = (const char*)P + ((size_t)dv << 10) + 512 + il * 32;\
        stage16(srow, pn);          stage16(srow + 16, pn + 1024);             \
        stage16(drow, pn + 2048);   stage16(drow + 16, pn + 3072); }

    // ---- prologue: FIFO after = [P0(4), idx2, P1(4), idx3] = 10 ----
    stage4(IDX_GADDR(0), ib + 0 * 256);
    stage4(IDX_GADDR(1), ib + 1 * 256);
    asm volatile("s_waitcnt vmcnt(0)" ::: "memory");
    __builtin_amdgcn_sched_barrier(0);
    ISSUE_P(0);
    stage4(IDX_GADDR(2), ib + 2 * 256);
    ISSUE_P(1);
    stage4(IDX_GADDR(3), ib + 3 * 256);

    // ---- main loop (fully unrolled; r compile-time) ----
    #pragma unroll
    for (int r = 0; r < K3_ROUNDS; ++r) {
        if (r == 0)       { asm volatile("s_waitcnt vmcnt(5)" ::: "memory"); }
        else if (r == 1)  { asm volatile("s_waitcnt vmcnt(6)" ::: "memory"); }
        else if (r <= 12) { asm volatile("s_waitcnt vmcnt(7)" ::: "memory"); }
        else if (r <= 14) { asm volatile("s_waitcnt vmcnt(6)" ::: "memory"); }
        else              { asm volatile("s_waitcnt vmcnt(2)" ::: "memory"); }
        __builtin_amdgcn_sched_barrier(0);

        // ---- read phase: pull round-r data LDS -> regs BEFORE overwriting ----
        const char* pcur = pb + (r & 1) * 4096;
        const char* icur = ib + (r % 5) * 256;
        float2 qv = *(const float2*)(icur + 32 + 8 * g);
        u32x4 a0 = *(const u32x4*)(pcur + lane * 16);
        u32x4 a1 = *(const u32x4*)(pcur + 1024 + lane * 16);
        u32x4 c0 = *(const u32x4*)(pcur + 2048 + lane * 16);
        u32x4 c1 = *(const u32x4*)(pcur + 3072 + lane * 16);
        __builtin_amdgcn_sched_barrier(0);   // reads strictly before DMA overwrite

        // ---- issue phase: P[r+2] into pb[r&1], idx[r+4] ----
        if (r + 2 < K3_ROUNDS) ISSUE_P(r + 2);                       // rounds 0..13
        if (r + 4 < K3_ROUNDS) stage4(IDX_GADDR(r + 4), ib + ((r + 4) % 5) * 256); // 0..11
        __builtin_amdgcn_sched_barrier(0);   // issues strictly before compute/store

        // ---- compute round r ----
        h2 p0 = (h2){(_Float16)qv.x, (_Float16)qv.x};
        h2 p1 = (h2){(_Float16)qv.y, (_Float16)qv.y};
        h2 z[8];
        float sum = 0.f, ss = 0.f;
        #pragma unroll
        for (int p = 0; p < 8; ++p) {
            h2 pv = pick(a0, a1, p) + pick(c0, c1, p);
            h2 cc = w0c[p] * p0 + w1c[p] * p1;
            z[p] = pv + cc;
            sum = fdot2(z[p], onep, sum);
            ss  = fdot2(z[p], z[p], ss);
        }
        sum = reduce16(sum); ss = reduce16(ss);
        float mu   = sum * (1.0f / 256.0f);
        float var  = ss * (1.0f / 256.0f) - mu * mu;
        float rstd = rsqrtf(var + 1e-5f);
        float nmur = -mu * rstd;
        h2 rsh = (h2){(_Float16)rstd, (_Float16)rstd};
        h2 nmh = (h2){(_Float16)nmur, (_Float16)nmur};
        float o0 = 0.f, o1 = 0.f;
        #pragma unroll
        for (int p = 0; p < 8; ++p) {
            h2 tt = z[p] * rsh + nmh;
            h2 u  = tt * gc[p] + bc[p];
            u = __builtin_elementwise_max(u, zerop);
            o0 = fdot2(u, w2ac[p], o0);
            o1 = fdot2(u, w2bc[p], o1);
        }
        o0 = reduce16(o0); o1 = reduce16(o1);
        int eg = ebase + g + r * K3_STRIDE;
        if (il == 0 && eg < EE)     // exec-zero only possible at r=15 (after last counted wait)
            *(float2*)(out + 2 * (size_t)eg) = make_float2(o0 + b20, o1 + b21);
    }
    #undef ISSUE_P
    #undef IDX_GADDR
    asm volatile("s_waitcnt vmcnt(0)" ::: "memory");   // drain stores
}

extern "C" void kernel_launch(void* const* d_in, const int* in_sizes, int n_in,
                              void* d_out, int out_size, void* d_ws, size_t ws_size,
                              hipStream_t stream) {
    const float* h     = (const float*)d_in[0];
    const float* cls   = (const float*)d_in[1];
    const float* polar = (const float*)d_in[2];
    const int*   src   = (const int*)d_in[3];
    const int*   dst   = (const int*)d_in[4];
    const float* W1    = (const float*)d_in[5];
    const float* b1    = (const float*)d_in[6];
    const float* gamma = (const float*)d_in[7];
    const float* beta  = (const float*)d_in[8];
    const float* W2    = (const float*)d_in[9];
    const float* b2    = (const float*)d_in[10];
    float* out = (float*)d_out;

    char* ws = (char*)d_ws;
    _Float16*       P   = (_Float16*)ws;                      // N*512*2 = 102,400,000 B
    unsigned short* W1T = (unsigned short*)(ws + 102400000);  // 131,072 B
    uint4*          CT  = (uint4*)(ws + 102531072);           // 3,072 B

    build_w1t_ct<<<257, 256, 0, stream>>>(W1, gamma, beta, W2, W1T, CT);
    p_gemm<<<1563, 256, 0, stream>>>(h, cls, W1T, b1, P);
    edge_kernel<<<K3_BLOCKS, 256, 0, stream>>>(P, src, dst, polar, CT, b2, out);
}